// Round 5
// baseline (546.186 us; speedup 1.0000x reference)
//
#include <hip/hip_runtime.h>
#include <hip/hip_bf16.h>
#include <math.h>

// GATv2 3-layer GNN, MI355X. CSR-by-dst + fused online-softmax aggregation.
// R2: parallel pooling. R3: register-tiled fp32 linear.
// R4: k_fused defer-max + branchless lrelu + 2-edge unroll per slot.

__device__ __forceinline__ float elu1(float x) { return x > 0.f ? x : expm1f(x); }

__device__ __forceinline__ unsigned f2ord(float x) {
    unsigned b = __float_as_uint(x);
    return (b & 0x80000000u) ? ~b : (b | 0x80000000u);
}
__device__ __forceinline__ float ord2f(unsigned u) {
    unsigned b = (u & 0x80000000u) ? (u & 0x7FFFFFFFu) : ~u;
    return __uint_as_float(b);
}

// ---------------- CSR build ----------------
__global__ void k_zero_i32(int* __restrict__ p, int n) {
    int i = blockIdx.x * blockDim.x + threadIdx.x;
    if (i < n) p[i] = 0;
}

__global__ void k_hist(const int* __restrict__ ei, int E, int N, int* __restrict__ deg) {
    int e = blockIdx.x * blockDim.x + threadIdx.x;
    int Etot = E + N;
    if (e >= Etot) return;
    int d = (e < E) ? ei[E + e] : (e - E);
    atomicAdd(&deg[d], 1);
}

__global__ void __launch_bounds__(1024) k_scan(const int* __restrict__ deg, int n,
                                               int* __restrict__ row_off, int* __restrict__ cursor) {
    __shared__ int wsum[16];
    __shared__ int sbase;
    int tid = threadIdx.x;
    int lane = tid & 63, w = tid >> 6;
    if (tid == 0) sbase = 0;
    __syncthreads();
    for (int start = 0; start < n; start += 1024) {
        int i = start + tid;
        int v = (i < n) ? deg[i] : 0;
        int s = v;
        #pragma unroll
        for (int d = 1; d < 64; d <<= 1) {
            int t = __shfl_up(s, d, 64);
            if (lane >= d) s += t;
        }
        if (lane == 63) wsum[w] = s;
        __syncthreads();
        int wbase = 0;
        for (int k = 0; k < w; k++) wbase += wsum[k];
        int excl = sbase + wbase + (s - v);
        if (i < n) { row_off[i] = excl; cursor[i] = excl; }
        __syncthreads();
        if (tid == 1023) sbase = excl + v;
        __syncthreads();
    }
    if (tid == 0) row_off[n] = sbase;
}

__global__ void k_scatter(const int* __restrict__ ei, int E, int N,
                          int* __restrict__ cursor,
                          int* __restrict__ csr_src) {
    int e = blockIdx.x * blockDim.x + threadIdx.x;
    int Etot = E + N;
    if (e >= Etot) return;
    int s, d;
    if (e < E) { s = ei[e]; d = ei[E + e]; } else { s = e - E; d = e - E; }
    int p = atomicAdd(&cursor[d], 1);
    csr_src[p] = s;
}

// ---------------- register-tiled dual linear ----------------
template <int K, int MH>
__global__ void k_linear2(const float* __restrict__ x, int N,
                          const float* __restrict__ Wl, const float* __restrict__ bl,
                          const float* __restrict__ Wr, const float* __restrict__ br,
                          float* __restrict__ xl, float* __restrict__ xr) {
    constexpr int NCG = MH / 2;
    __shared__ float xs[32 * K];
    int tid = threadIdx.x;
    int node0 = blockIdx.x * 32;
    for (int idx = tid * 4; idx < 32 * K; idx += NCG * 4 * 4) {
        int node = node0 + idx / K;
        float4 v = make_float4(0.f, 0.f, 0.f, 0.f);
        if (node < N) v = *(const float4*)(x + (size_t)node0 * K + idx);
        *(float4*)(xs + idx) = v;
    }
    __syncthreads();

    int cg = tid % NCG;
    int ng = tid / NCG;
    bool rightSide = cg >= (MH / 4);
    int c = (rightSide ? cg - MH / 4 : cg) * 4;
    const float* W  = rightSide ? Wr : Wl;
    const float* bb = rightSide ? br : bl;
    float* out      = rightSide ? xr : xl;

    float acc[8][4];
    #pragma unroll
    for (int i = 0; i < 8; i++)
        #pragma unroll
        for (int j = 0; j < 4; j++) acc[i][j] = 0.f;

    const float* xrow = xs + ng * 8 * K;
    for (int k0 = 0; k0 < K; k0 += 4) {
        float4 wv[4];
        #pragma unroll
        for (int kk = 0; kk < 4; kk++)
            wv[kk] = *(const float4*)(W + (size_t)(k0 + kk) * MH + c);
        #pragma unroll
        for (int i = 0; i < 8; i++) {
            float4 xv = *(const float4*)(xrow + i * K + k0);
            float xvk[4] = {xv.x, xv.y, xv.z, xv.w};
            #pragma unroll
            for (int kk = 0; kk < 4; kk++) {
                acc[i][0] += xvk[kk] * wv[kk].x;
                acc[i][1] += xvk[kk] * wv[kk].y;
                acc[i][2] += xvk[kk] * wv[kk].z;
                acc[i][3] += xvk[kk] * wv[kk].w;
            }
        }
    }
    float4 bv = *(const float4*)(bb + c);
    #pragma unroll
    for (int i = 0; i < 8; i++) {
        int node = node0 + ng * 8 + i;
        if (node < N) {
            float4 o = make_float4(acc[i][0] + bv.x, acc[i][1] + bv.y,
                                   acc[i][2] + bv.z, acc[i][3] + bv.w);
            *(float4*)(out + (size_t)node * MH + c) = o;
        }
    }
}

// ---------------- fused online-softmax attention + aggregate ----------------
template <int CPL>
__device__ __forceinline__ void loadrow(const float* __restrict__ p, float* v) {
    if constexpr (CPL == 8) {
        float4 a = ((const float4*)p)[0];
        float4 b = ((const float4*)p)[1];
        v[0] = a.x; v[1] = a.y; v[2] = a.z; v[3] = a.w;
        v[4] = b.x; v[5] = b.y; v[6] = b.z; v[7] = b.w;
    } else {
        float2 a = ((const float2*)p)[0];
        v[0] = a.x; v[1] = a.y;
    }
}

// wave per dst node; 4 edge-slots x 16 lanes; 2-edge unroll; defer-max online softmax.
template <int HC, int C>
__global__ void __launch_bounds__(256) k_fused(
        const int* __restrict__ row_off, const int* __restrict__ csr_src,
        const float* __restrict__ xl, const float* __restrict__ xr,
        const float* __restrict__ att, const float* __restrict__ bias,
        float* __restrict__ hout, int N) {
    constexpr int CPL = HC / 16;
    constexpr int GROUP = (16 * C) / HC;
    int wid = (blockIdx.x * blockDim.x + threadIdx.x) >> 6;
    int lane = threadIdx.x & 63;
    if (wid >= N) return;
    int slot = lane >> 4;
    int j = lane & 15;
    int c0 = j * CPL;

    int p0 = row_off[wid], p1 = row_off[wid + 1];

    float xrv[CPL], attv[CPL];
    loadrow<CPL>(xr + (size_t)wid * HC + c0, xrv);
    loadrow<CPL>(att + c0, attv);

    float m = -INFINITY, den = 0.f;
    float acc[CPL];
    #pragma unroll
    for (int q = 0; q < CPL; q++) acc[q] = 0.f;

    int p = p0 + slot;
    int s0 = (p < p1) ? csr_src[p] : 0;
    int s1 = (p + 4 < p1) ? csr_src[p + 4] : 0;
    while (p < p1) {
        int np = p + 8;
        int ns0 = (np < p1) ? csr_src[np] : 0;          // prefetch next pair's indices
        int ns1 = (np + 4 < p1) ? csr_src[np + 4] : 0;
        bool has2 = (p + 4) < p1;
        float xa[CPL], xb[CPL];
        loadrow<CPL>(xl + (size_t)s0 * HC + c0, xa);    // two gathers in flight
        loadrow<CPL>(xl + (size_t)s1 * HC + c0, xb);
        float pa = 0.f, pb = 0.f;
        #pragma unroll
        for (int q = 0; q < CPL; q++) {
            float ta = xa[q] + xrv[q];
            float tb = xb[q] + xrv[q];
            pa = fmaf(fmaxf(ta, 0.2f * ta), attv[q], pa);   // branchless leaky-relu
            pb = fmaf(fmaxf(tb, 0.2f * tb), attv[q], pb);
        }
        #pragma unroll
        for (int msk = 1; msk < GROUP; msk <<= 1) {
            pa += __shfl_xor(pa, msk, 64);
            pb += __shfl_xor(pb, msk, 64);
        }
        // defer-max online update (THR=8): rescale only on big new max
        if (pa > m + 8.f) {
            float corr = __expf(m - pa);   // m=-inf -> 0 (zeroes empty state)
            den *= corr;
            #pragma unroll
            for (int q = 0; q < CPL; q++) acc[q] *= corr;
            m = pa;
        }
        float ea = __expf(pa - m);
        den += ea;
        #pragma unroll
        for (int q = 0; q < CPL; q++) acc[q] = fmaf(ea, xa[q], acc[q]);
        if (has2) {
            if (pb > m + 8.f) {
                float corr = __expf(m - pb);
                den *= corr;
                #pragma unroll
                for (int q = 0; q < CPL; q++) acc[q] *= corr;
                m = pb;
            }
            float eb = __expf(pb - m);
            den += eb;
            #pragma unroll
            for (int q = 0; q < CPL; q++) acc[q] = fmaf(eb, xb[q], acc[q]);
        }
        p = np; s0 = ns0; s1 = ns1;
    }
    // combine the 4 slots (flash-style rescale; works with deferred m references)
    float mAll = fmaxf(m, __shfl_xor(m, 16, 64));
    mAll = fmaxf(mAll, __shfl_xor(mAll, 32, 64));
    float scale = __expf(m - mAll);      // -inf slot -> 0
    float dtot = den * scale;
    dtot += __shfl_xor(dtot, 16, 64);
    dtot += __shfl_xor(dtot, 32, 64);
    #pragma unroll
    for (int q = 0; q < CPL; q++) {
        float a = acc[q] * scale;
        a += __shfl_xor(a, 16, 64);
        a += __shfl_xor(a, 32, 64);
        acc[q] = a;
    }
    if (slot == 0) {
        float inv = 1.0f / (dtot + 1e-16f);
        #pragma unroll
        for (int q = 0; q < CPL; q++) {
            float v = acc[q] * inv + bias[c0 + q];
            hout[(size_t)wid * HC + c0 + q] = elu1(v);
        }
    }
}

// ---------------- graph pooling (parallel, 2-stage) ----------------
__global__ void __launch_bounds__(256) k_pool_partial(
        const float* __restrict__ h, const int* __restrict__ batch, int N, int G,
        float* __restrict__ gsum, unsigned* __restrict__ gmax) {
    __shared__ float lsum[512];
    __shared__ unsigned lmax[512];
    int tid = threadIdx.x;
    for (int i = tid; i < G * 32; i += 256) { lsum[i] = 0.f; lmax[i] = 0u; }
    __syncthreads();
    int chunk = (N + gridDim.x - 1) / gridDim.x;
    int start = blockIdx.x * chunk;
    int end = min(N, start + chunk);
    int col = tid & 31, row = tid >> 5;
    int gc = -1; float ps = 0.f; unsigned pm = 0u;
    for (int i = start + row; i < end; i += 8) {
        int g = batch[i];
        if (g != gc) {
            if (gc >= 0) { atomicAdd(&lsum[gc * 32 + col], ps); atomicMax(&lmax[gc * 32 + col], pm); }
            gc = g; ps = 0.f; pm = 0u;
        }
        float v = h[(size_t)i * 32 + col];
        ps += v; pm = max(pm, f2ord(v));
    }
    if (gc >= 0) { atomicAdd(&lsum[gc * 32 + col], ps); atomicMax(&lmax[gc * 32 + col], pm); }
    __syncthreads();
    for (int i = tid; i < G * 32; i += 256) {
        if (lmax[i]) {
            atomicAdd(&gsum[i], lsum[i]);
            atomicMax(&gmax[i], lmax[i]);
        }
    }
}

__global__ void k_pool_final(const float* __restrict__ gsum, const unsigned* __restrict__ gmax,
                             const int* __restrict__ batch, int N, float* __restrict__ out) {
    int g = blockIdx.x;
    int t = threadIdx.x;
    __shared__ int s_cnt;
    if (t == 0) {
        int lo = 0, hi = N;
        while (lo < hi) { int m = (lo + hi) >> 1; if (batch[m] < g) lo = m + 1; else hi = m; }
        int a = lo;
        lo = a; hi = N;
        while (lo < hi) { int m = (lo + hi) >> 1; if (batch[m] < g + 1) lo = m + 1; else hi = m; }
        s_cnt = lo - a;
    }
    __syncthreads();
    if (t < 32) {
        out[g * 64 + t] = gsum[g * 32 + t] / (float)max(s_cnt, 1);
    } else {
        out[g * 64 + t] = ord2f(gmax[g * 32 + (t - 32)]);
    }
}

extern "C" void kernel_launch(void* const* d_in, const int* in_sizes, int n_in,
                              void* d_out, int out_size, void* d_ws, size_t ws_size,
                              hipStream_t stream) {
    const float* x      = (const float*)d_in[0];
    const int*   ei     = (const int*)d_in[1];
    const int*   batch  = (const int*)d_in[2];
    const float* Wl1 = (const float*)d_in[3],  *bl1 = (const float*)d_in[4];
    const float* Wr1 = (const float*)d_in[5],  *br1 = (const float*)d_in[6];
    const float* att1= (const float*)d_in[7],  *b1  = (const float*)d_in[8];
    const float* Wl2 = (const float*)d_in[9],  *bl2 = (const float*)d_in[10];
    const float* Wr2 = (const float*)d_in[11], *br2 = (const float*)d_in[12];
    const float* att2= (const float*)d_in[13], *b2  = (const float*)d_in[14];
    const float* Wl3 = (const float*)d_in[15], *bl3 = (const float*)d_in[16];
    const float* Wr3 = (const float*)d_in[17], *br3 = (const float*)d_in[18];
    const float* att3= (const float*)d_in[19], *b3  = (const float*)d_in[20];

    int N = in_sizes[0] / 8;
    int E = in_sizes[1] / 2;
    int G = out_size / 64;
    int Etot = E + N;

    char* w = (char*)d_ws;
    auto carve = [&](size_t bytes) {
        void* p = (void*)w;
        w += (bytes + 255) & ~(size_t)255;
        return p;
    };
    int*      deg     = (int*)carve((size_t)N * 4);
    int*      row_off = (int*)carve((size_t)(N + 1) * 4);
    int*      cursor  = (int*)carve((size_t)N * 4);
    int*      csr_src = (int*)carve((size_t)Etot * 4);
    float*    gsum    = (float*)carve((size_t)G * 32 * 4);
    unsigned* gmax    = (unsigned*)carve((size_t)G * 32 * 4);
    float*    bufA    = (float*)carve((size_t)N * 128 * 4);  // xl
    float*    bufB    = (float*)carve((size_t)N * 128 * 4);  // xr
    float*    bufC    = (float*)carve((size_t)N * 128 * 4);  // h (layer outputs)
    (void)ws_size; (void)n_in;

    // ---- CSR by dst (incl. self loops) + pool accumulator init ----
    k_zero_i32<<<(N + 255) / 256, 256, 0, stream>>>(deg, N);
    k_zero_i32<<<(2 * G * 32 + 255) / 256, 256, 0, stream>>>((int*)gsum, 2 * G * 32);
    k_hist<<<(Etot + 255) / 256, 256, 0, stream>>>(ei, E, N, deg);
    k_scan<<<1, 1024, 0, stream>>>(deg, N, row_off, cursor);
    k_scatter<<<(Etot + 255) / 256, 256, 0, stream>>>(ei, E, N, cursor, csr_src);

    int grdLin = (N + 31) / 32;
    int grdFused = (N + 3) / 4;

    // ---- Layer 1: K=8 -> 128 (H=2,C=64) ----
    k_linear2<8, 128><<<grdLin, 256, 0, stream>>>(x, N, Wl1, bl1, Wr1, br1, bufA, bufB);
    k_fused<128, 64><<<grdFused, 256, 0, stream>>>(row_off, csr_src, bufA, bufB, att1, b1, bufC, N);

    // ---- Layer 2: 128 -> 128 ----
    k_linear2<128, 128><<<grdLin, 256, 0, stream>>>(bufC, N, Wl2, bl2, Wr2, br2, bufA, bufB);
    k_fused<128, 64><<<grdFused, 256, 0, stream>>>(row_off, csr_src, bufA, bufB, att2, b2, bufC, N);

    // ---- Layer 3: 128 -> 32 (H=1,C=32) ----
    k_linear2<128, 32><<<grdLin, 64, 0, stream>>>(bufC, N, Wl3, bl3, Wr3, br3, bufA, bufB);
    k_fused<32, 32><<<grdFused, 256, 0, stream>>>(row_off, csr_src, bufA, bufB, att3, b3, bufC, N);

    // ---- pooling ----
    k_pool_partial<<<256, 256, 0, stream>>>(bufC, batch, N, G, gsum, gmax);
    k_pool_final<<<G, 64, 0, stream>>>(gsum, gmax, batch, N, (float*)d_out);
}